// Round 5
// baseline (747.655 us; speedup 1.0000x reference)
//
#include <hip/hip_runtime.h>
#include <hip/hip_bf16.h>
#include <math.h>

#define N_NODES 100000
#define N_EDGES 1600000
#define IN_DIM  768
#define HIDDEN  256

#define SCAN_B  256
#define N_SBLK  ((N_NODES + SCAN_B - 1) / SCAN_B)   // 391

// ---- ws layout (bytes), all offsets 16B-aligned ----
#define H_OFF    0ull                  // bf16 h' [N_NODES][HIDDEN]     51,200,000 B
#define ADJ_OFF  51200000ull           // int adj [N_EDGES]              6,400,000 B
#define RS_OFF   57600000ull           // int row_start [N_NODES+1]        400,004 B
#define CUR_OFF  58000016ull           // int cursor [N_NODES]             400,000 B
#define DEG_OFF  58400016ull           // int deg [N_NODES]                400,000 B
#define DINV_OFF 58800016ull           // float dinv [N_NODES]             400,000 B
#define W1T_OFF  59200016ull           // bf16 W1t [HIDDEN][IN_DIM]        393,216 B
#define BSUM_OFF 59593232ull           // int bsum [N_SBLK]                  1,564 B
// total ~59.6 MB

typedef short          bf16x8 __attribute__((ext_vector_type(8)));
typedef float          fp32x4 __attribute__((ext_vector_type(4)));
typedef unsigned short u16x4  __attribute__((ext_vector_type(4)));

__device__ inline short f2bf(float f) {
    union { float f; unsigned u; } c; c.f = f;
    unsigned u = c.u;
    unsigned r = u + 0x7FFFu + ((u >> 16) & 1u);   // RNE
    return (short)(r >> 16);
}

__device__ inline fp32x4 bf4_to_f4(u16x4 v) {
    fp32x4 r;
    for (int j = 0; j < 4; j++) {
        union { unsigned u; float f; } c;
        c.u = ((unsigned)v[j]) << 16;
        r[j] = c.f;
    }
    return r;
}

// async global->LDS, 16B per lane (wave-uniform dest base + lane*16)
__device__ inline void async16(const void* g, void* l) {
    __builtin_amdgcn_global_load_lds(
        (const __attribute__((address_space(1))) unsigned int*)g,
        (__attribute__((address_space(3))) unsigned int*)l,
        16, 0, 0);
}

// ---------------- init: zero deg + cursor ----------------
__global__ void init_kernel(int* __restrict__ deg, int* __restrict__ cursor) {
    int i = blockIdx.x * blockDim.x + threadIdx.x;
    if (i < N_NODES) { deg[i] = 0; cursor[i] = 0; }
}

// ---------------- W1 -> W1t (bf16, [HIDDEN][IN_DIM]) ----------------
__global__ void w1t_kernel(const float* __restrict__ w1, short* __restrict__ w1t) {
    int i = blockIdx.x * blockDim.x + threadIdx.x;
    if (i < HIDDEN * IN_DIM) {
        int n = i / IN_DIM, k = i % IN_DIM;
        w1t[i] = f2bf(w1[(size_t)k * HIDDEN + n]);
    }
}

// ---------------- count in-degree (real edges only) ----------------
__global__ void count_kernel(const int* __restrict__ dst, int* __restrict__ deg) {
    int e = blockIdx.x * blockDim.x + threadIdx.x;
    if (e < N_EDGES) atomicAdd(&deg[dst[e]], 1);
}

// ---------------- scan phase 1: per-block sums ----------------
__global__ __launch_bounds__(SCAN_B) void scan1_kernel(const int* __restrict__ deg,
                                                       int* __restrict__ bsum) {
    int i = blockIdx.x * SCAN_B + threadIdx.x;
    int v = (i < N_NODES) ? deg[i] : 0;
    for (int off = 32; off > 0; off >>= 1) v += __shfl_down(v, off, 64);
    __shared__ int wsum[SCAN_B / 64];
    int lane = threadIdx.x & 63, w = threadIdx.x >> 6;
    if (lane == 0) wsum[w] = v;
    __syncthreads();
    if (threadIdx.x == 0) {
        int s = 0;
        for (int j = 0; j < SCAN_B / 64; j++) s += wsum[j];
        bsum[blockIdx.x] = s;
    }
}

// ---------------- scan phase 2: exclusive-scan the block sums (1 block) ----------------
__global__ __launch_bounds__(512) void scan2_kernel(int* __restrict__ bsum) {
    __shared__ int s[512];
    int tid = threadIdx.x;
    int v = (tid < N_SBLK) ? bsum[tid] : 0;
    s[tid] = v;
    __syncthreads();
    for (int off = 1; off < 512; off <<= 1) {
        int t = (tid >= off) ? s[tid - off] : 0;
        __syncthreads();
        s[tid] += t;
        __syncthreads();
    }
    if (tid < N_SBLK) bsum[tid] = s[tid] - v;   // exclusive
}

// ---------------- scan phase 3: block-local scan + offset; also dinv ----------------
__global__ __launch_bounds__(SCAN_B) void scan3_kernel(const int* __restrict__ deg,
                                                       const int* __restrict__ bsum,
                                                       int* __restrict__ row_start,
                                                       float* __restrict__ dinv) {
    __shared__ int s[SCAN_B];
    int i = blockIdx.x * SCAN_B + threadIdx.x;
    int tid = threadIdx.x;
    int d = (i < N_NODES) ? deg[i] : 0;
    s[tid] = d;
    __syncthreads();
    for (int off = 1; off < SCAN_B; off <<= 1) {
        int t = (tid >= off) ? s[tid - off] : 0;
        __syncthreads();
        s[tid] += t;
        __syncthreads();
    }
    if (i < N_NODES) {
        row_start[i] = bsum[blockIdx.x] + s[tid] - d;   // exclusive
        dinv[i] = rsqrtf((float)(d + 1));               // +1 self loop
        if (i == N_NODES - 1) row_start[N_NODES] = N_EDGES;  // deg sums to N_EDGES
    }
}

// ---------------- fill CSR adjacency (src list grouped by dst) ----------------
__global__ void fill_kernel(const int* __restrict__ src, const int* __restrict__ dst,
                            const int* __restrict__ row_start, int* __restrict__ cursor,
                            int* __restrict__ adj) {
    int e = blockIdx.x * blockDim.x + threadIdx.x;
    if (e < N_EDGES) {
        int d = dst[e];
        int p = row_start[d] + atomicAdd(&cursor[d], 1);
        adj[p] = src[e];
    }
}

// ---------------- GEMM1: h'[r] = bf16(dinv[r] * (x[r] @ W1)) ----------------
// Block tile 128 rows x 256 cols (full HIDDEN), 512 threads = 8 waves (2x4),
// wave tile 64x64, BK=32.
//   B: global_load_lds width-16, TRIPLE-buffered (3x16KB). Step t stages tile
//      t+2; barrier uses counted s_waitcnt vmcnt(2) (T4) so tile t+2's loads
//      stay in flight ACROSS the barrier -- no full drain per step (the old
//      __syncthreads emitted vmcnt(0) and drained the issue-early loads).
//   A: reg-staged (fp32 -> regs -> f2bf -> ds_write_b128), double-buffered,
//      T14 split: na loads issued FIRST (oldest -> AWRITE's dependency waits
//      vmcnt(2), leaving BSTAGE in flight), convert+write after MFMA.
// Swizzle both tiles: 16B slot s_mem = s0 ^ ((row>>1)&3) -> 2-way free reads.
// LDS = 2x8KB (A) + 3x16KB (B) = 64 KB -> 2 blocks/CU.
__global__ __launch_bounds__(512) void gemm1_kernel(const float* __restrict__ x,
                                                    const short* __restrict__ w1t,
                                                    const float* __restrict__ dinv,
                                                    unsigned short* __restrict__ h) {
    __shared__ __align__(16) short a_lds[2 * 128 * 32];   // 2 x 8 KB bf16
    __shared__ __align__(16) short b_lds[3 * 256 * 32];   // 3 x 16 KB bf16

    const int tid  = threadIdx.x;
    const int lane = tid & 63;
    const int wave = tid >> 6;          // 0..7
    const int wm = (wave >> 2) * 64;    // 0 or 64
    const int wn = (wave & 3) * 64;     // 0,64,128,192
    const int l15 = lane & 15;
    const int q   = lane >> 4;
    const int NT  = IN_DIM / 32;        // 24

    // bijective XCD-chunked swizzle (nwg=782, 8 XCDs)
    const int nwg = gridDim.x;
    const int xq = nwg >> 3, xr = nwg & 7;
    const int orig = blockIdx.x;
    const int xcd = orig & 7, idx = orig >> 3;
    const int wgid = (xcd < xr ? xcd * (xq + 1) : xr * (xq + 1) + (xcd - xr) * xq) + idx;
    const int row0 = wgid * 128;

    // ---- A staging geometry (reg path) ----
    const int ar = tid >> 2;
    const int kq = tid & 3;
    int garow = row0 + ar;
    if (garow >= N_NODES) garow = N_NODES - 1;   // clamp: OOB rows never stored
    const float* axp = x + (size_t)garow * IN_DIM + kq * 8;
    const int asw  = (ar >> 1) & 3;
    const int aoff = ar * 32 + ((kq ^ asw) << 3);   // shorts

    // ---- B staging geometry (global_load_lds) ----
    const short* bg[2];
    int blo[2];
#pragma unroll
    for (int i = 0; i < 2; i++) {
        int cd = (wave * 2 + i) * 64 + lane;
        int br = cd >> 2;          // 0..255
        int c  = cd & 3;
        bg[i]  = w1t + (size_t)br * IN_DIM + ((c ^ ((br >> 1) & 3)) * 8);
        blo[i] = cd * 16;   // bytes
    }

    fp32x4 acc[4][4];
#pragma unroll
    for (int i = 0; i < 4; i++)
#pragma unroll
        for (int j = 0; j < 4; j++)
#pragma unroll
            for (int r = 0; r < 4; r++) acc[i][j][r] = 0.0f;

#define BSTAGE(buf, k0) do {                                                  \
        char* bb = (char*)(b_lds + (buf) * (256 * 32));                       \
        async16(bg[0] + (k0), bb + blo[0]);                                   \
        async16(bg[1] + (k0), bb + blo[1]);                                   \
    } while (0)

#define AWRITE(buf, v0, v1) do {                                              \
        short* ad = a_lds + (buf) * (128 * 32);                               \
        bf16x8 wv;                                                            \
        wv[0] = f2bf(v0[0]); wv[1] = f2bf(v0[1]);                             \
        wv[2] = f2bf(v0[2]); wv[3] = f2bf(v0[3]);                             \
        wv[4] = f2bf(v1[0]); wv[5] = f2bf(v1[1]);                             \
        wv[6] = f2bf(v1[2]); wv[7] = f2bf(v1[3]);                             \
        *(bf16x8*)(ad + aoff) = wv;                                           \
    } while (0)

// counted-vmcnt barrier: tile t+1's B loads (older) must be done; tile t+2's
// two global_load_lds (newest) may remain in flight. ds_writes drained (lgkm).
#define KBAR() do {                                                           \
        asm volatile("s_waitcnt vmcnt(2) lgkmcnt(0)" ::: "memory");           \
        __builtin_amdgcn_s_barrier();                                         \
    } while (0)

    // prologue: A t0 + B t0, then B t1 in flight
    {
        fp32x4 p0 = *(const fp32x4*)(axp + 0);
        fp32x4 p1 = *(const fp32x4*)(axp + 4);
        BSTAGE(0, 0);
        AWRITE(0, p0, p1);          // waits p0/p1 (older than BSTAGE0? issued
                                    // first textually; correctness either way)
        BSTAGE(1, 32);
        KBAR();                     // B t0 resident; B t1 may stay in flight
    }

    const int fsw = q ^ ((l15 >> 1) & 3);   // frag-read slot (const per lane)

    int cur = 0;        // A buffer holding tile t
    int bread = 0;      // B buffer holding tile t
    int btgt = 2;       // B buffer to stage tile t+2 into
    for (int t = 0; t < NT; ++t) {
        const int kn = (t + 1) * 32;
        const bool haveA = kn < IN_DIM;
        fp32x4 na0, na1;
        if (haveA) {
            // A loads FIRST (oldest) so AWRITE's wait leaves BSTAGE in flight
            na0 = *(const fp32x4*)(axp + kn);
            na1 = *(const fp32x4*)(axp + kn + 4);
        }
        if (t + 2 < NT) BSTAGE(btgt, (t + 2) * 32);
        __builtin_amdgcn_sched_barrier(0);   // keep the issue cluster on top

        // compute tile t (B t landed before previous barrier)
        const short* ac = a_lds + cur * (128 * 32);
        const short* bc = b_lds + bread * (256 * 32);
        bf16x8 af[4], bfr[4];
#pragma unroll
        for (int mt = 0; mt < 4; mt++)
            af[mt] = *(const bf16x8*)(ac + (wm + mt * 16 + l15) * 32 + (fsw << 3));
#pragma unroll
        for (int nt = 0; nt < 4; nt++)
            bfr[nt] = *(const bf16x8*)(bc + (wn + nt * 16 + l15) * 32 + (fsw << 3));
#pragma unroll
        for (int mt = 0; mt < 4; mt++)
#pragma unroll
            for (int nt = 0; nt < 4; nt++)
                acc[mt][nt] = __builtin_amdgcn_mfma_f32_16x16x32_bf16(
                    af[mt], bfr[nt], acc[mt][nt], 0, 0, 0);

        // write-late: convert A t+1 and commit to the other A buffer.
        // WAR safe: that buffer's reads finished before the previous barrier.
        if (haveA) AWRITE(cur ^ 1, na0, na1);

        KBAR();
        cur ^= 1;
        bread = (bread == 2) ? 0 : bread + 1;
        btgt  = (btgt  == 2) ? 0 : btgt  + 1;
    }
#undef BSTAGE
#undef AWRITE
#undef KBAR

    // epilogue: h'[row][col] = bf16(dinv[row] * acc)
    float dv[4][4];
#pragma unroll
    for (int mt = 0; mt < 4; mt++)
#pragma unroll
        for (int r = 0; r < 4; r++) {
            int row = row0 + wm + mt * 16 + q * 4 + r;
            dv[mt][r] = (row < N_NODES) ? dinv[row] : 0.0f;
        }
#pragma unroll
    for (int mt = 0; mt < 4; mt++) {
#pragma unroll
        for (int nt = 0; nt < 4; nt++) {
            int col = wn + nt * 16 + l15;
#pragma unroll
            for (int r = 0; r < 4; r++) {
                int row = row0 + wm + mt * 16 + q * 4 + r;
                if (row < N_NODES)
                    h[(size_t)row * HIDDEN + col] =
                        (unsigned short)f2bf(dv[mt][r] * acc[mt][nt][r]);
            }
        }
    }
}

// ---------------- aggregate + bias + relu + W2 + log_softmax ----------------
// one wave per dst node; lane holds 4 of the 256 hidden channels (bf16 h').
// adj indices read as wave-uniform broadcast loads (e0/e1 are wave-uniform):
// head-peel to 16B alignment, then int4 per 4 edges with 1-ahead prefetch.
// No __shfl on the gather critical path; adj read exactly once.
__global__ __launch_bounds__(256) void aggregate_kernel(
    const unsigned short* __restrict__ h, const int* __restrict__ adj,
    const int* __restrict__ row_start, const float* __restrict__ dinv,
    const float* __restrict__ b1, const float* __restrict__ w2,
    const float* __restrict__ b2, float* __restrict__ out) {
    const int lane = threadIdx.x & 63;
    const int wave = threadIdx.x >> 6;
    const int v = blockIdx.x * 4 + wave;
    if (v >= N_NODES) return;

    const size_t loff = (size_t)lane * 4;

    // self-loop term: h'[v] (already dinv[v]*h[v])
    fp32x4 a0 = bf4_to_f4(*(const u16x4*)(h + (size_t)v * HIDDEN + loff));
    fp32x4 a1 = {0,0,0,0}, a2 = {0,0,0,0}, a3 = {0,0,0,0};

    const int e0 = row_start[v], e1 = row_start[v + 1];
    int e = e0;
    // head-peel to 4-edge alignment (adj is 16B-aligned at index%4==0)
    while ((e & 3) && e < e1) {
        int si = adj[e];
        a0 += bf4_to_f4(*(const u16x4*)(h + (size_t)si * HIDDEN + loff));
        ++e;
    }
    if (e + 4 <= e1) {
        int4 ss = *(const int4*)(adj + e);
        for (; e + 4 <= e1; e += 4) {
            int4 nx = ss;
            if (e + 8 <= e1) ss = *(const int4*)(adj + e + 4);   // prefetch
            u16x4 r0 = *(const u16x4*)(h + (size_t)nx.x * HIDDEN + loff);
            u16x4 r1 = *(const u16x4*)(h + (size_t)nx.y * HIDDEN + loff);
            u16x4 r2 = *(const u16x4*)(h + (size_t)nx.z * HIDDEN + loff);
            u16x4 r3 = *(const u16x4*)(h + (size_t)nx.w * HIDDEN + loff);
            a0 += bf4_to_f4(r0);
            a1 += bf4_to_f4(r1);
            a2 += bf4_to_f4(r2);
            a3 += bf4_to_f4(r3);
        }
    }
    for (; e < e1; ++e) {
        int si = adj[e];
        a0 += bf4_to_f4(*(const u16x4*)(h + (size_t)si * HIDDEN + loff));
    }
    fp32x4 acc = (a0 + a1) + (a2 + a3);

    float dvv = dinv[v];
    fp32x4 bb = *(const fp32x4*)(b1 + loff);
    float hr[4];
    for (int j = 0; j < 4; j++) hr[j] = fmaxf(0.0f, dvv * acc[j] + bb[j]);

    float p0 = 0.f, p1 = 0.f, p2 = 0.f;
    for (int j = 0; j < 4; j++) {
        const float* wr = w2 + (size_t)(lane * 4 + j) * 3;
        p0 += hr[j] * wr[0];
        p1 += hr[j] * wr[1];
        p2 += hr[j] * wr[2];
    }
    for (int off = 32; off > 0; off >>= 1) {
        p0 += __shfl_down(p0, off, 64);
        p1 += __shfl_down(p1, off, 64);
        p2 += __shfl_down(p2, off, 64);
    }
    if (lane == 0) {
        p0 += b2[0]; p1 += b2[1]; p2 += b2[2];
        float m = fmaxf(p0, fmaxf(p1, p2));
        float l = logf(expf(p0 - m) + expf(p1 - m) + expf(p2 - m));
        out[(size_t)v * 3 + 0] = p0 - m - l;
        out[(size_t)v * 3 + 1] = p1 - m - l;
        out[(size_t)v * 3 + 2] = p2 - m - l;
    }
}

extern "C" void kernel_launch(void* const* d_in, const int* in_sizes, int n_in,
                              void* d_out, int out_size, void* d_ws, size_t ws_size,
                              hipStream_t stream) {
    const float* x    = (const float*)d_in[0];
    const int*   ei   = (const int*)d_in[1];      // [2][N_EDGES]
    const float* W1   = (const float*)d_in[2];
    const float* b1   = (const float*)d_in[3];
    const float* W2   = (const float*)d_in[4];
    const float* b2   = (const float*)d_in[5];
    float* out = (float*)d_out;

    const int* src = ei;
    const int* dst = ei + N_EDGES;

    char* ws = (char*)d_ws;
    unsigned short* h_ws = (unsigned short*)(ws + H_OFF);
    int*   adj       = (int*)(ws + ADJ_OFF);
    int*   row_start = (int*)(ws + RS_OFF);
    int*   cursor    = (int*)(ws + CUR_OFF);
    int*   deg       = (int*)(ws + DEG_OFF);
    float* dinv      = (float*)(ws + DINV_OFF);
    short* w1t       = (short*)(ws + W1T_OFF);
    int*   bsum      = (int*)(ws + BSUM_OFF);

    init_kernel<<<(N_NODES + 255) / 256, 256, 0, stream>>>(deg, cursor);
    w1t_kernel<<<(HIDDEN * IN_DIM + 255) / 256, 256, 0, stream>>>(W1, w1t);
    count_kernel<<<(N_EDGES + 255) / 256, 256, 0, stream>>>(dst, deg);
    scan1_kernel<<<N_SBLK, SCAN_B, 0, stream>>>(deg, bsum);
    scan2_kernel<<<1, 512, 0, stream>>>(bsum);
    scan3_kernel<<<N_SBLK, SCAN_B, 0, stream>>>(deg, bsum, row_start, dinv);
    fill_kernel<<<(N_EDGES + 255) / 256, 256, 0, stream>>>(src, dst, row_start, cursor, adj);
    gemm1_kernel<<<(N_NODES + 127) / 128, 512, 0, stream>>>(x, w1t, dinv, h_ws);
    aggregate_kernel<<<N_NODES / 4, 256, 0, stream>>>(h_ws, adj, row_start, dinv, b1, W2, b2, out);
}

// Round 6
// 733.916 us; speedup vs baseline: 1.0187x; 1.0187x over previous
//
#include <hip/hip_runtime.h>
#include <hip/hip_bf16.h>
#include <math.h>

#define N_NODES 100000
#define N_EDGES 1600000
#define IN_DIM  768
#define HIDDEN  256

#define SCAN_B  256
#define N_SBLK  ((N_NODES + SCAN_B - 1) / SCAN_B)   // 391

// ---- ws layout (bytes), all offsets 16B-aligned ----
#define H_OFF    0ull                  // bf16 h' [N_NODES][HIDDEN]     51,200,000 B
#define ADJ_OFF  51200000ull           // int adj [N_EDGES]              6,400,000 B
#define RS_OFF   57600000ull           // int row_start [N_NODES+1]        400,004 B
#define CUR_OFF  58000016ull           // int cursor [N_NODES]             400,000 B
#define DEG_OFF  58400016ull           // int deg [N_NODES]                400,000 B
#define DINV_OFF 58800016ull           // float dinv [N_NODES]             400,000 B
#define W1T_OFF  59200016ull           // bf16 W1t [HIDDEN][IN_DIM]        393,216 B
#define BSUM_OFF 59593232ull           // int bsum [N_SBLK]                  1,564 B
// total ~59.6 MB

typedef short          bf16x8 __attribute__((ext_vector_type(8)));
typedef float          fp32x4 __attribute__((ext_vector_type(4)));
typedef unsigned short u16x4  __attribute__((ext_vector_type(4)));
typedef unsigned short u16x8  __attribute__((ext_vector_type(8)));
typedef float          fp32x8 __attribute__((ext_vector_type(8)));

__device__ inline short f2bf(float f) {
    union { float f; unsigned u; } c; c.f = f;
    unsigned u = c.u;
    unsigned r = u + 0x7FFFu + ((u >> 16) & 1u);   // RNE
    return (short)(r >> 16);
}

__device__ inline fp32x8 bf8_to_f8(u16x8 v) {
    fp32x8 r;
    for (int j = 0; j < 8; j++) {
        union { unsigned u; float f; } c;
        c.u = ((unsigned)v[j]) << 16;
        r[j] = c.f;
    }
    return r;
}

// async global->LDS, 16B per lane (wave-uniform dest base + lane*16)
__device__ inline void async16(const void* g, void* l) {
    __builtin_amdgcn_global_load_lds(
        (const __attribute__((address_space(1))) unsigned int*)g,
        (__attribute__((address_space(3))) unsigned int*)l,
        16, 0, 0);
}

// ---------------- init: zero deg + cursor ----------------
__global__ void init_kernel(int* __restrict__ deg, int* __restrict__ cursor) {
    int i = blockIdx.x * blockDim.x + threadIdx.x;
    if (i < N_NODES) { deg[i] = 0; cursor[i] = 0; }
}

// ---------------- W1 -> W1t (bf16, [HIDDEN][IN_DIM]) ----------------
__global__ void w1t_kernel(const float* __restrict__ w1, short* __restrict__ w1t) {
    int i = blockIdx.x * blockDim.x + threadIdx.x;
    if (i < HIDDEN * IN_DIM) {
        int n = i / IN_DIM, k = i % IN_DIM;
        w1t[i] = f2bf(w1[(size_t)k * HIDDEN + n]);
    }
}

// ---------------- count in-degree (real edges only) ----------------
__global__ void count_kernel(const int* __restrict__ dst, int* __restrict__ deg) {
    int e = blockIdx.x * blockDim.x + threadIdx.x;
    if (e < N_EDGES) atomicAdd(&deg[dst[e]], 1);
}

// ---------------- scan phase 1: per-block sums ----------------
__global__ __launch_bounds__(SCAN_B) void scan1_kernel(const int* __restrict__ deg,
                                                       int* __restrict__ bsum) {
    int i = blockIdx.x * SCAN_B + threadIdx.x;
    int v = (i < N_NODES) ? deg[i] : 0;
    for (int off = 32; off > 0; off >>= 1) v += __shfl_down(v, off, 64);
    __shared__ int wsum[SCAN_B / 64];
    int lane = threadIdx.x & 63, w = threadIdx.x >> 6;
    if (lane == 0) wsum[w] = v;
    __syncthreads();
    if (threadIdx.x == 0) {
        int s = 0;
        for (int j = 0; j < SCAN_B / 64; j++) s += wsum[j];
        bsum[blockIdx.x] = s;
    }
}

// ---------------- scan phase 2: exclusive-scan the block sums (1 block) ----------------
__global__ __launch_bounds__(512) void scan2_kernel(int* __restrict__ bsum) {
    __shared__ int s[512];
    int tid = threadIdx.x;
    int v = (tid < N_SBLK) ? bsum[tid] : 0;
    s[tid] = v;
    __syncthreads();
    for (int off = 1; off < 512; off <<= 1) {
        int t = (tid >= off) ? s[tid - off] : 0;
        __syncthreads();
        s[tid] += t;
        __syncthreads();
    }
    if (tid < N_SBLK) bsum[tid] = s[tid] - v;   // exclusive
}

// ---------------- scan phase 3: block-local scan + offset; also dinv ----------------
__global__ __launch_bounds__(SCAN_B) void scan3_kernel(const int* __restrict__ deg,
                                                       const int* __restrict__ bsum,
                                                       int* __restrict__ row_start,
                                                       float* __restrict__ dinv) {
    __shared__ int s[SCAN_B];
    int i = blockIdx.x * SCAN_B + threadIdx.x;
    int tid = threadIdx.x;
    int d = (i < N_NODES) ? deg[i] : 0;
    s[tid] = d;
    __syncthreads();
    for (int off = 1; off < SCAN_B; off <<= 1) {
        int t = (tid >= off) ? s[tid - off] : 0;
        __syncthreads();
        s[tid] += t;
        __syncthreads();
    }
    if (i < N_NODES) {
        row_start[i] = bsum[blockIdx.x] + s[tid] - d;   // exclusive
        dinv[i] = rsqrtf((float)(d + 1));               // +1 self loop
        if (i == N_NODES - 1) row_start[N_NODES] = N_EDGES;  // deg sums to N_EDGES
    }
}

// ---------------- fill CSR adjacency (src list grouped by dst) ----------------
__global__ void fill_kernel(const int* __restrict__ src, const int* __restrict__ dst,
                            const int* __restrict__ row_start, int* __restrict__ cursor,
                            int* __restrict__ adj) {
    int e = blockIdx.x * blockDim.x + threadIdx.x;
    if (e < N_EDGES) {
        int d = dst[e];
        int p = row_start[d] + atomicAdd(&cursor[d], 1);
        adj[p] = src[e];
    }
}

// ---------------- GEMM1: h'[r] = bf16(dinv[r] * (x[r] @ W1)) ----------------
// (round-4 version, best measured: 128 rows x 256 cols, double-buffered,
//  one __syncthreads per K-step; 48 KB LDS -> 3 blocks/CU)
__global__ __launch_bounds__(512) void gemm1_kernel(const float* __restrict__ x,
                                                    const short* __restrict__ w1t,
                                                    const float* __restrict__ dinv,
                                                    unsigned short* __restrict__ h) {
    __shared__ __align__(16) short a_lds[2 * 128 * 32];   // 2 x 8 KB bf16
    __shared__ __align__(16) short b_lds[2 * 256 * 32];   // 2 x 16 KB bf16

    const int tid  = threadIdx.x;
    const int lane = tid & 63;
    const int wave = tid >> 6;          // 0..7
    const int wm = (wave >> 2) * 64;    // 0 or 64
    const int wn = (wave & 3) * 64;     // 0,64,128,192
    const int l15 = lane & 15;
    const int q   = lane >> 4;

    // bijective XCD-chunked swizzle (nwg=782, 8 XCDs)
    const int nwg = gridDim.x;
    const int xq = nwg >> 3, xr = nwg & 7;
    const int orig = blockIdx.x;
    const int xcd = orig & 7, idx = orig >> 3;
    const int wgid = (xcd < xr ? xcd * (xq + 1) : xr * (xq + 1) + (xcd - xr) * xq) + idx;
    const int row0 = wgid * 128;

    // ---- A staging geometry (reg path) ----
    const int ar = tid >> 2;
    const int kq = tid & 3;
    int garow = row0 + ar;
    if (garow >= N_NODES) garow = N_NODES - 1;   // clamp: OOB rows never stored
    const float* axp = x + (size_t)garow * IN_DIM + kq * 8;
    const int asw  = (ar >> 1) & 3;
    const int aoff = ar * 32 + ((kq ^ asw) << 3);   // shorts

    // ---- B staging geometry (global_load_lds) ----
    const short* bg[2];
    int blo[2];
#pragma unroll
    for (int i = 0; i < 2; i++) {
        int cd = (wave * 2 + i) * 64 + lane;
        int br = cd >> 2;          // 0..255
        int c  = cd & 3;
        bg[i]  = w1t + (size_t)br * IN_DIM + ((c ^ ((br >> 1) & 3)) * 8);
        blo[i] = cd * 16;   // bytes
    }

    fp32x4 acc[4][4];
#pragma unroll
    for (int i = 0; i < 4; i++)
#pragma unroll
        for (int j = 0; j < 4; j++)
#pragma unroll
            for (int r = 0; r < 4; r++) acc[i][j][r] = 0.0f;

#define BSTAGE(buf, k0) do {                                                  \
        char* bb = (char*)(b_lds + (buf) * (256 * 32));                       \
        async16(bg[0] + (k0), bb + blo[0]);                                   \
        async16(bg[1] + (k0), bb + blo[1]);                                   \
    } while (0)

#define AWRITE(buf, v0, v1) do {                                              \
        short* ad = a_lds + (buf) * (128 * 32);                               \
        bf16x8 wv;                                                            \
        wv[0] = f2bf(v0[0]); wv[1] = f2bf(v0[1]);                             \
        wv[2] = f2bf(v0[2]); wv[3] = f2bf(v0[3]);                             \
        wv[4] = f2bf(v1[0]); wv[5] = f2bf(v1[1]);                             \
        wv[6] = f2bf(v1[2]); wv[7] = f2bf(v1[3]);                             \
        *(bf16x8*)(ad + aoff) = wv;                                           \
    } while (0)

    // prologue: tile 0
    {
        fp32x4 na0 = *(const fp32x4*)(axp + 0);
        fp32x4 na1 = *(const fp32x4*)(axp + 4);
        BSTAGE(0, 0);
        AWRITE(0, na0, na1);
        __syncthreads();   // drains A writes (lgkm) + B asyncs (vmcnt)
    }

    const int fsw = q ^ ((l15 >> 1) & 3);   // frag-read slot (const per lane)

    int cur = 0;
    for (int t = 0; t < IN_DIM / 32; ++t) {
        const int kn = (t + 1) * 32;
        const bool more = kn < IN_DIM;
        fp32x4 na0, na1;
        if (more) {
            // issue-early: next A tile into regs, next B tile via async DMA
            na0 = *(const fp32x4*)(axp + kn);
            na1 = *(const fp32x4*)(axp + kn + 4);
            BSTAGE(cur ^ 1, kn);
        }

        // compute tile t (pure bf16 ds_read + MFMA; loads above stay in flight)
        const short* ac = a_lds + cur * (128 * 32);
        const short* bc = b_lds + cur * (256 * 32);
        bf16x8 af[4], bfr[4];
#pragma unroll
        for (int mt = 0; mt < 4; mt++)
            af[mt] = *(const bf16x8*)(ac + (wm + mt * 16 + l15) * 32 + (fsw << 3));
#pragma unroll
        for (int nt = 0; nt < 4; nt++)
            bfr[nt] = *(const bf16x8*)(bc + (wn + nt * 16 + l15) * 32 + (fsw << 3));
#pragma unroll
        for (int mt = 0; mt < 4; mt++)
#pragma unroll
            for (int nt = 0; nt < 4; nt++)
                acc[mt][nt] = __builtin_amdgcn_mfma_f32_16x16x32_bf16(
                    af[mt], bfr[nt], acc[mt][nt], 0, 0, 0);

        // write-late: convert next A tile and commit to the other buffer.
        // Safe without an extra barrier: buf cur^1 was last READ in step t-1,
        // whose reads were ordered before the step-(t-1) __syncthreads.
        if (more) AWRITE(cur ^ 1, na0, na1);

        __syncthreads();   // B asyncs + A writes for tile t+1 resident
        cur ^= 1;
    }
#undef BSTAGE
#undef AWRITE

    // epilogue: h'[row][col] = bf16(dinv[row] * acc)
    float dv[4][4];
#pragma unroll
    for (int mt = 0; mt < 4; mt++)
#pragma unroll
        for (int r = 0; r < 4; r++) {
            int row = row0 + wm + mt * 16 + q * 4 + r;
            dv[mt][r] = (row < N_NODES) ? dinv[row] : 0.0f;
        }
#pragma unroll
    for (int mt = 0; mt < 4; mt++) {
#pragma unroll
        for (int nt = 0; nt < 4; nt++) {
            int col = wn + nt * 16 + l15;
#pragma unroll
            for (int r = 0; r < 4; r++) {
                int row = row0 + wm + mt * 16 + q * 4 + r;
                if (row < N_NODES)
                    h[(size_t)row * HIDDEN + col] =
                        (unsigned short)f2bf(dv[mt][r] * acc[mt][nt][r]);
            }
        }
    }
}

// ---------------- aggregate + bias + relu + W2 + log_softmax ----------------
// one wave per dst node, PAIR-GATHER layout: lanes 0-31 hold edge i's 256
// channels (8 ch = 16 B per lane), lanes 32-63 hold edge i+1's. One wave
// gather instruction covers TWO edges at 16 B/lane (vs 1 edge at 8 B/lane):
// halves VMEM instruction count, same bytes. Self-loop = virtual edge 0.
// Halves folded at the end via __shfl_xor(32); W2 reduce over 32 lanes.
__global__ __launch_bounds__(256) void aggregate_kernel(
    const unsigned short* __restrict__ h, const int* __restrict__ adj,
    const int* __restrict__ row_start, const float* __restrict__ dinv,
    const float* __restrict__ b1, const float* __restrict__ w2,
    const float* __restrict__ b2, float* __restrict__ out) {
    const int lane = threadIdx.x & 63;
    const int wave = threadIdx.x >> 6;
    const int v = blockIdx.x * 4 + wave;
    if (v >= N_NODES) return;

    const int half = lane >> 5;            // 0: even edges, 1: odd edges
    const size_t coff = (size_t)(lane & 31) * 8;   // 8 channels per lane

    fp32x8 a0 = {0,0,0,0,0,0,0,0}, a1 = a0, a2 = a0, a3 = a0;

    const int e0 = row_start[v], e1 = row_start[v + 1];
    const int total = (e1 - e0) + 1;       // virtual edge 0 = self-loop (v)

    for (int base = 0; base < total; base += 64) {
        const int cnt = min(64, total - base);
        const int gi = base + lane;
        int s = v;
        if (lane < cnt && gi > 0) s = adj[e0 + gi - 1];
        int i = 0;
        for (; i + 8 <= cnt; i += 8) {     // 4 pairs = 8 edges in flight
            int sA0 = __shfl(s, i,     64), sB0 = __shfl(s, i + 1, 64);
            int sA1 = __shfl(s, i + 2, 64), sB1 = __shfl(s, i + 3, 64);
            int sA2 = __shfl(s, i + 4, 64), sB2 = __shfl(s, i + 5, 64);
            int sA3 = __shfl(s, i + 6, 64), sB3 = __shfl(s, i + 7, 64);
            int s0 = half ? sB0 : sA0;
            int s1 = half ? sB1 : sA1;
            int s2 = half ? sB2 : sA2;
            int s3 = half ? sB3 : sA3;
            u16x8 r0 = *(const u16x8*)(h + (size_t)s0 * HIDDEN + coff);
            u16x8 r1 = *(const u16x8*)(h + (size_t)s1 * HIDDEN + coff);
            u16x8 r2 = *(const u16x8*)(h + (size_t)s2 * HIDDEN + coff);
            u16x8 r3 = *(const u16x8*)(h + (size_t)s3 * HIDDEN + coff);
            a0 += bf8_to_f8(r0);
            a1 += bf8_to_f8(r1);
            a2 += bf8_to_f8(r2);
            a3 += bf8_to_f8(r3);
        }
        for (; i + 2 <= cnt; i += 2) {     // leftover pairs
            int sA = __shfl(s, i, 64), sB = __shfl(s, i + 1, 64);
            int si = half ? sB : sA;
            a0 += bf8_to_f8(*(const u16x8*)(h + (size_t)si * HIDDEN + coff));
        }
        if (i < cnt) {                     // odd tail: half 0 only
            int si = __shfl(s, i, 64);
            if (half == 0)
                a1 += bf8_to_f8(*(const u16x8*)(h + (size_t)si * HIDDEN + coff));
        }
    }
    fp32x8 acc = (a0 + a1) + (a2 + a3);
    // fold halves: lane L and L^32 hold even/odd partial sums for the SAME
    // 8 channels -> one xor-32 shuffle pass makes every lane hold the total.
#pragma unroll
    for (int j = 0; j < 8; j++) acc[j] += __shfl_xor(acc[j], 32, 64);

    const float dvv = dinv[v];
    float hr[8];
#pragma unroll
    for (int j = 0; j < 8; j++)
        hr[j] = fmaxf(0.0f, dvv * acc[j] + b1[coff + j]);

    float p0 = 0.f, p1 = 0.f, p2 = 0.f;
#pragma unroll
    for (int j = 0; j < 8; j++) {
        const float* wr = w2 + (coff + j) * 3;
        p0 += hr[j] * wr[0];
        p1 += hr[j] * wr[1];
        p2 += hr[j] * wr[2];
    }
    // channels live on lanes 0..31 (lanes 32+ hold duplicates): 32-lane reduce
    for (int off = 16; off > 0; off >>= 1) {
        p0 += __shfl_down(p0, off, 64);
        p1 += __shfl_down(p1, off, 64);
        p2 += __shfl_down(p2, off, 64);
    }
    if (lane == 0) {
        p0 += b2[0]; p1 += b2[1]; p2 += b2[2];
        float m = fmaxf(p0, fmaxf(p1, p2));
        float l = logf(expf(p0 - m) + expf(p1 - m) + expf(p2 - m));
        out[(size_t)v * 3 + 0] = p0 - m - l;
        out[(size_t)v * 3 + 1] = p1 - m - l;
        out[(size_t)v * 3 + 2] = p2 - m - l;
    }
}

extern "C" void kernel_launch(void* const* d_in, const int* in_sizes, int n_in,
                              void* d_out, int out_size, void* d_ws, size_t ws_size,
                              hipStream_t stream) {
    const float* x    = (const float*)d_in[0];
    const int*   ei   = (const int*)d_in[1];      // [2][N_EDGES]
    const float* W1   = (const float*)d_in[2];
    const float* b1   = (const float*)d_in[3];
    const float* W2   = (const float*)d_in[4];
    const float* b2   = (const float*)d_in[5];
    float* out = (float*)d_out;

    const int* src = ei;
    const int* dst = ei + N_EDGES;

    char* ws = (char*)d_ws;
    unsigned short* h_ws = (unsigned short*)(ws + H_OFF);
    int*   adj       = (int*)(ws + ADJ_OFF);
    int*   row_start = (int*)(ws + RS_OFF);
    int*   cursor    = (int*)(ws + CUR_OFF);
    int*   deg       = (int*)(ws + DEG_OFF);
    float* dinv      = (float*)(ws + DINV_OFF);
    short* w1t       = (short*)(ws + W1T_OFF);
    int*   bsum      = (int*)(ws + BSUM_OFF);

    init_kernel<<<(N_NODES + 255) / 256, 256, 0, stream>>>(deg, cursor);
    w1t_kernel<<<(HIDDEN * IN_DIM + 255) / 256, 256, 0, stream>>>(W1, w1t);
    count_kernel<<<(N_EDGES + 255) / 256, 256, 0, stream>>>(dst, deg);
    scan1_kernel<<<N_SBLK, SCAN_B, 0, stream>>>(deg, bsum);
    scan2_kernel<<<1, 512, 0, stream>>>(bsum);
    scan3_kernel<<<N_SBLK, SCAN_B, 0, stream>>>(deg, bsum, row_start, dinv);
    fill_kernel<<<(N_EDGES + 255) / 256, 256, 0, stream>>>(src, dst, row_start, cursor, adj);
    gemm1_kernel<<<(N_NODES + 127) / 128, 512, 0, stream>>>(x, w1t, dinv, h_ws);
    aggregate_kernel<<<N_NODES / 4, 256, 0, stream>>>(h_ws, adj, row_start, dinv, b1, W2, b2, out);
}